// Round 6
// baseline (99.503 us; speedup 1.0000x reference)
//
#include <hip/hip_runtime.h>

#define NTH 256
#define U1H_STRIDE 21504  // 8*1024 + 8*512 + 8*256 + 56*128

#define PHI1 0.29504296f    // e^{-1.220703125}
#define PHI2 0.0075683594f  // e^{-4.8828125}
#define GCUT 18.0f          // Gaussian support cutoff: e^-18 = 1.5e-8

// ---------------- common helpers ----------------
__device__ __forceinline__ int swz(int i) { return i ^ (((i >> 4) & 3) * 5); }

__device__ __forceinline__ float2 cmul(float2 a, float2 b) {
  return make_float2(a.x * b.x - a.y * b.y, a.x * b.y + a.y * b.x);
}

template <int W>
__device__ __forceinline__ float wsum(float v) {
#pragma unroll
  for (int off = 1; off < W; off <<= 1) v += __shfl_xor(v, off, 64);
  return v;
}

__device__ __forceinline__ float2 shflx2(float2 v, int mask) {
  return make_float2(__shfl_xor(v.x, mask, 64), __shfl_xor(v.y, mask, 64));
}

// ---------------- register radix-2 FFT (per lane-group) ----------------
// Layout: element e = r*LANES + l; x[r] in registers.
// rdif: natural -> bit-reversed (DIF). INV=true gives inverse (e^{+i}) twiddles.
template <int M, int LANES, bool INV>
__device__ __forceinline__ void rdif(float2* x, int l) {
  constexpr int R = M / LANES;
#pragma unroll
  for (int half = R / 2; half >= 1; half >>= 1) {  // spans s = half*LANES
    const int s = half * LANES;
    const float a0 = (INV ? 3.14159265358979f : -3.14159265358979f) / (float)s;
#pragma unroll
    for (int r = 0; r < R; ++r) {
      if ((r & half) == 0) {
        const float2 a = x[r], b = x[r + half];
        const int j = (r & (half - 1)) * LANES + l;
        float2 w; __sincosf(a0 * (float)j, &w.y, &w.x);
        x[r] = make_float2(a.x + b.x, a.y + b.y);
        x[r + half] = cmul(make_float2(a.x - b.x, a.y - b.y), w);
      }
    }
  }
#pragma unroll
  for (int s = LANES / 2; s >= 1; s >>= 1) {  // cross-lane spans
    const float a0 = (INV ? 3.14159265358979f : -3.14159265358979f) / (float)s;
    float2 w; __sincosf(a0 * (float)(l & (s - 1)), &w.y, &w.x);
    const bool hi = (l & s) != 0;
#pragma unroll
    for (int r = 0; r < R; ++r) {
      const float2 y = shflx2(x[r], s);
      const float2 sum = make_float2(x[r].x + y.x, x[r].y + y.y);
      const float2 dif = cmul(make_float2(y.x - x[r].x, y.y - x[r].y), w);
      x[r] = hi ? dif : sum;
    }
  }
}

// rdit: bit-reversed -> natural (DIT). INV=false is the forward transform.
template <int M, int LANES, bool INV>
__device__ __forceinline__ void rdit(float2* x, int l) {
  constexpr int R = M / LANES;
#pragma unroll
  for (int s = 1; s <= LANES / 2; s <<= 1) {  // cross-lane first
    const float a0 = (INV ? 3.14159265358979f : -3.14159265358979f) / (float)s;
    float2 w; __sincosf(a0 * (float)(l & (s - 1)), &w.y, &w.x);
    const bool hi = (l & s) != 0;
#pragma unroll
    for (int r = 0; r < R; ++r) {
      const float2 y = shflx2(x[r], s);
      const float2 wb = cmul(w, hi ? x[r] : y);
      x[r] = hi ? make_float2(y.x - wb.x, y.y - wb.y)
                : make_float2(x[r].x + wb.x, x[r].y + wb.y);
    }
  }
#pragma unroll
  for (int half = 1; half <= R / 2; half <<= 1) {  // within-lane
    const int s = half * LANES;
    const float a0 = (INV ? 3.14159265358979f : -3.14159265358979f) / (float)s;
#pragma unroll
    for (int r = 0; r < R; ++r) {
      if ((r & half) == 0) {
        const int j = (r & (half - 1)) * LANES + l;
        float2 w; __sincosf(a0 * (float)j, &w.y, &w.x);
        const float2 bw = cmul(x[r + half], w);
        const float2 a = x[r];
        x[r] = make_float2(a.x + bw.x, a.y + bw.y);
        x[r + half] = make_float2(a.x - bw.x, a.y - bw.y);
      }
    }
  }
}

// ---------------- kA: 2048-pt block LDS FFT (unchanged, small) -------------
template <bool INV>
__device__ __forceinline__ void dif4(float2* A, int j, int ls, float astep) {
  const int s = 1 << ls;
  const int e = j & (s - 1);
  const int base = ((j >> ls) << (ls + 2)) | e;
  float2 w1;
  __sincosf(astep * (float)e, &w1.y, &w1.x);
  if (INV) w1.y = -w1.y;
  const float2 w2 = cmul(w1, w1);
  const float2 w3 = cmul(w2, w1);
  const float2 a0 = A[swz(base)];
  const float2 a1 = A[swz(base + s)];
  const float2 a2 = A[swz(base + 2 * s)];
  const float2 a3 = A[swz(base + 3 * s)];
  const float t0x = a0.x + a2.x, t0y = a0.y + a2.y;
  const float t1x = a0.x - a2.x, t1y = a0.y - a2.y;
  const float t2x = a1.x + a3.x, t2y = a1.y + a3.y;
  const float bdx = a1.x - a3.x, bdy = a1.y - a3.y;
  const float sgn = INV ? -1.0f : 1.0f;
  const float t3x = sgn * bdy, t3y = -sgn * bdx;
  A[swz(base)]         = make_float2(t0x + t2x, t0y + t2y);
  A[swz(base + s)]     = cmul(make_float2(t1x + t3x, t1y + t3y), w1);
  A[swz(base + 2 * s)] = cmul(make_float2(t0x - t2x, t0y - t2y), w2);
  A[swz(base + 3 * s)] = cmul(make_float2(t1x - t3x, t1y - t3y), w3);
}

__device__ __forceinline__ void r2pair(float2* A, int g) {
  const float2 a = A[swz(2 * g)];
  const float2 b = A[swz(2 * g + 1)];
  A[swz(2 * g)]     = make_float2(a.x + b.x, a.y + b.y);
  A[swz(2 * g + 1)] = make_float2(a.x - b.x, a.y - b.y);
}

__device__ __forceinline__ int prev2048(int i) {
  return ((i >> 9) & 3) | (((i >> 7) & 3) << 2) | (((i >> 5) & 3) << 4) |
         (((i >> 3) & 3) << 6) | (((i >> 1) & 3) << 8) | ((i & 1) << 10);
}

__global__ __launch_bounds__(NTH) void kA(const float* __restrict__ x,
                                          float2* __restrict__ xh) {
  __shared__ float2 A[2048];
  const int n = blockIdx.x, b = n / 6, c = n % 6;
  const float* xp = x + (size_t)b * (2048 * 6) + c;
#pragma unroll
  for (int i = 0; i < 8; ++i) {
    const int t = (int)threadIdx.x + NTH * i;
    A[swz(t)] = make_float2(xp[t * 6], 0.0f);
  }
  const int tid = (int)threadIdx.x;
#pragma unroll
  for (int ls = 9; ls >= 1; ls -= 2) {
    const float astep = -1.5707963267948966f / (float)(1 << ls);
    __syncthreads();
#pragma unroll
    for (int i = 0; i < 2; ++i) dif4<false>(A, tid + NTH * i, ls, astep);
  }
  __syncthreads();
#pragma unroll
  for (int i = 0; i < 4; ++i) r2pair(A, tid + NTH * i);
  __syncthreads();
#pragma unroll
  for (int i = 0; i < 8; ++i) {
    const int t = (int)threadIdx.x + NTH * i;
    xh[(size_t)n * 2048 + prev2048(t)] = A[swz(t)];
  }
}

// ---------------- layout / output helpers ----------------
__device__ __forceinline__ int u1h_off(int j1) {
  const int o = j1 >> 3;
  if (o == 0) return j1 * 1024;
  if (o == 1) return 8192 + (j1 - 8) * 512;
  if (o == 2) return 12288 + (j1 - 16) * 256;
  return 14336 + (j1 - 24) * 128;
}
__device__ __forceinline__ float* o1p(float* out, int b, int c, int j1) {
  return out + ((size_t)b * 440 + j1) * 6 + c;
}
__device__ __forceinline__ float* o2p(float* out, int b, int c, int j1, int k) {
  return out + ((size_t)b * 440 + 80 + 4 * k * (k - 1) + j1) * 6 + c;
}
__device__ __forceinline__ float xi2f(int k) { return 0.4f * exp2f(-(float)k); }

// ---------------- Stage B: parents, fully in registers ----------------
// lane = threadIdx & 63; group of LANES lanes owns one path.
template <int M1, int LANES>
__device__ __forceinline__ void parentR(const float2* __restrict__ src,
                                        float2* __restrict__ Vg,
                                        float* __restrict__ outp,
                                        int j1, int lane) {
  constexpr int R = M1 / LANES;
  constexpr int F = 2048 / M1;
  const int l = lane & (LANES - 1);
  const int gb = lane - l;
  const float xi = 0.4f * exp2f(-0.125f * (float)j1);
  const float sig = 0.1f * xi;
  const float i2s = 1.0f / (2.0f * sig * sig);
  float2 x[R];
#pragma unroll
  for (int r = 0; r < R; ++r) {
    const int m = r * LANES + l;
    float2 acc = make_float2(0.0f, 0.0f);
#pragma unroll
    for (int q = 0; q < F; ++q) {
      const int f = m + q * M1;
      const float fr = (float)(f < 1024 ? f : f - 2048) * (1.0f / 2048.0f);
      const float d = fr - xi;
      const float dd = d * d * i2s;
      if (dd < GCUT) {
        const float g = __expf(-dd);
        const float2 v = src[f];
        acc.x += v.x * g; acc.y += v.y * g;
      }
    }
    x[r] = acc;
  }
  rdif<M1, LANES, true>(x, l);   // inverse FFT, natural -> bitrev
#pragma unroll
  for (int r = 0; r < R; ++r)
    x[r] = make_float2(sqrtf(x[r].x * x[r].x + x[r].y * x[r].y) * (1.0f / 2048.0f), 0.0f);
  rdit<M1, LANES, false>(x, l);  // forward FFT, bitrev -> natural: V = U1h
#pragma unroll
  for (int r = 0; r < R; ++r) Vg[r * LANES + l] = x[r];  // coalesced
  const float invM = 1.0f / (float)M1;
  const float c0 = __shfl(x[0].x, gb, 64) * invM;
  const float2 U1 = make_float2(__shfl(x[0].x, gb + 1, 64), __shfl(x[0].y, gb + 1, 64));
  const float2 U2 = make_float2(__shfl(x[0].x, gb + 2, 64), __shfl(x[0].y, gb + 2, 64));
  const float k1 = PHI1 * 2.0f * invM, k2 = PHI2 * 2.0f * invM;
  float part = 0.0f;
#pragma unroll
  for (int r = 0; r < R; ++r) {
    const int t = r * LANES + l;
    float sv, cv;
    __sincosf((6.283185307179586f / (float)M1) * (float)t, &sv, &cv);
    float acc = c0 + k1 * (U1.x * cv - U1.y * sv);
    const float c2 = cv * cv - sv * sv, s2 = 2.0f * sv * cv;
    acc += k2 * (U2.x * c2 - U2.y * s2);
    part += __logf(acc + 1e-6f);
  }
  part = wsum<LANES>(part);
  if (l == 0) *outp = part * invM;
}

// kB: 13 classes/signal (624 blocks), zero LDS, zero barriers.
// [0,2) M1=1024 x4 waves; [2,4) 512 x4; [4,6) 256 x4; [6,13) 128 x8 halves.
__global__ __launch_bounds__(NTH, 4) void kB(const float2* __restrict__ xh,
                                             float2* __restrict__ U1h,
                                             float* __restrict__ out) {
  const int ci = (int)blockIdx.x / 48;
  const int n  = (int)blockIdx.x % 48;
  const int b = n / 6, c = n % 6;
  const float2* src = xh + (size_t)n * 2048;
  float2* Vb = U1h + (size_t)n * U1H_STRIDE;
  const int tid = (int)threadIdx.x;
  const int wid = tid >> 6, lane = tid & 63;
  const int h = lane >> 5;
  const int slot = 2 * wid + h;

  if (ci < 2) {
    const int j1 = 4 * ci + wid;
    parentR<1024, 64>(src, Vb + u1h_off(j1), o1p(out, b, c, j1), j1, lane);
  } else if (ci < 4) {
    const int j1 = 8 + 4 * (ci - 2) + wid;
    parentR<512, 64>(src, Vb + u1h_off(j1), o1p(out, b, c, j1), j1, lane);
  } else if (ci < 6) {
    const int j1 = 16 + 4 * (ci - 4) + wid;
    parentR<256, 64>(src, Vb + u1h_off(j1), o1p(out, b, c, j1), j1, lane);
  } else {
    const int j1 = 24 + 8 * (ci - 6) + slot;
    parentR<128, 32>(src, Vb + u1h_off(j1), o1p(out, b, c, j1), j1, lane);
  }
}

// ---------------- Stage C: descendants, fully in registers ----------------
template <int M2, int LANES>
__device__ __forceinline__ void descR(const float2* __restrict__ Vg,
                                      float* __restrict__ outp,
                                      int M1, int F, float xi, int lane) {
  constexpr int R = M2 / LANES;
  constexpr int LM = (M2 == 1024) ? 10 : (M2 == 512) ? 9 : (M2 == 256) ? 8 : 7;
  const int l = lane & (LANES - 1);
  const float sg = 0.8f * xi;
  const float i2s = 1.0f / (2.0f * sg * sg);
  float2 x[R];
#pragma unroll
  for (int r = 0; r < R; ++r) {
    const int m = r * LANES + l;
    float2 acc = make_float2(0.0f, 0.0f);
    for (int q = 0; q < F; ++q) {
      const int f = m + q * M2;
      const float fr = (float)(f < (M1 >> 1) ? f : f - M1) * (1.0f / 2048.0f);
      const float d = fr - xi;
      const float dd = d * d * i2s;
      if (dd < GCUT) {
        const float g = __expf(-dd);
        const float2 vv = Vg[f];
        acc.x += vv.x * g; acc.y += vv.y * g;
      }
    }
    x[r] = acc;
  }
  rdif<M2, LANES, true>(x, l);  // inverse FFT, natural -> bitrev
  const float invM1f = 1.0f / (float)M1;
  float b0 = 0, b1r = 0, b1i = 0, b2r = 0, b2i = 0;
#pragma unroll
  for (int r = 0; r < R; ++r) {
    const float u = sqrtf(x[r].x * x[r].x + x[r].y * x[r].y) * invM1f;
    const int e = r * LANES + l;
    const int t = (int)(__brev((unsigned)e) >> (32 - LM));
    float sv, cv;
    __sincosf((6.283185307179586f / (float)M2) * (float)t, &sv, &cv);
    b0 += u;
    b1r += u * cv; b1i -= u * sv;
    const float c2 = cv * cv - sv * sv, s2 = 2.0f * sv * cv;
    b2r += u * c2; b2i -= u * s2;
  }
  b0 = wsum<LANES>(b0);
  b1r = wsum<LANES>(b1r); b1i = wsum<LANES>(b1i);
  b2r = wsum<LANES>(b2r); b2i = wsum<LANES>(b2i);
  const float k1 = 2.0f * PHI1, k2 = 2.0f * PHI2;
  const float invM2 = 1.0f / (float)M2;
  float part = 0.0f;
#pragma unroll
  for (int r = 0; r < R; ++r) {
    const int e = r * LANES + l;
    const int t = (int)(__brev((unsigned)e) >> (32 - LM));
    float sv, cv;
    __sincosf((6.283185307179586f / (float)M2) * (float)t, &sv, &cv);
    float acc = b0 + k1 * (b1r * cv - b1i * sv);
    const float c2 = cv * cv - sv * sv, s2 = 2.0f * sv * cv;
    acc += k2 * (b2r * c2 - b2i * s2);
    part += __logf(acc * invM2 + 1e-6f);
  }
  part = wsum<LANES>(part);
  if (l == 0) *outp = part * invM2;
}

// kC: 52 classes/signal (2496 blocks), zero LDS, zero barriers.
// [0,2)  k=1 M2=1024 x4; [2,6)  k=2 M2=512 x4; [6,8)  k=3 M2=512 x4;
// [8,12) k=3 M2=256 x4; [12,14) k=4 M2=256 x4; [14,17) k=4 M2=128 x8;
// [17,52) k=5..9 M2=128 x8.
__global__ __launch_bounds__(NTH, 4) void kC(const float2* __restrict__ U1h,
                                             float* __restrict__ out) {
  const int ci = (int)blockIdx.x / 48;
  const int n  = (int)blockIdx.x % 48;
  const int b = n / 6, c = n % 6;
  const float2* Vb = U1h + (size_t)n * U1H_STRIDE;
  const int tid = (int)threadIdx.x;
  const int wid = tid >> 6, lane = tid & 63;
  const int h = lane >> 5;
  const int slot = 2 * wid + h;

  if (ci < 2) {
    const int j1 = 4 * ci + wid;  // 0..7
    descR<1024, 64>(Vb + u1h_off(j1), o2p(out, b, c, j1, 1), 1024, 1, xi2f(1), lane);
  } else if (ci < 6) {
    const int j1 = 4 * (ci - 2) + wid;  // 0..15
    const int M1 = (j1 < 8) ? 1024 : 512;
    descR<512, 64>(Vb + u1h_off(j1), o2p(out, b, c, j1, 2), M1, M1 / 512, xi2f(2), lane);
  } else if (ci < 8) {
    const int j1 = 4 * (ci - 6) + wid;  // 0..7
    descR<512, 64>(Vb + u1h_off(j1), o2p(out, b, c, j1, 3), 1024, 2, xi2f(3), lane);
  } else if (ci < 12) {
    const int j1 = 8 + 4 * (ci - 8) + wid;  // 8..23
    const int M1 = (j1 < 16) ? 512 : 256;
    descR<256, 64>(Vb + u1h_off(j1), o2p(out, b, c, j1, 3), M1, M1 / 256, xi2f(3), lane);
  } else if (ci < 14) {
    const int j1 = 4 * (ci - 12) + wid;  // 0..7
    descR<256, 64>(Vb + u1h_off(j1), o2p(out, b, c, j1, 4), 1024, 4, xi2f(4), lane);
  } else if (ci < 17) {
    const int j1 = 8 + 8 * (ci - 14) + slot;  // 8..31
    const int o = j1 >> 3;                    // 1..3
    const int M1 = (o < 3) ? (1024 >> o) : 128;
    descR<128, 32>(Vb + u1h_off(j1), o2p(out, b, c, j1, 4), M1, M1 / 128, xi2f(4), lane);
  } else {
    int g = ci - 17;  // k classes per k, k=5..9 (5+6+7+8+9 = 35)
    int k = 5;
    while (g >= k) { g -= k; ++k; }
    const int j1 = 8 * g + slot;  // octave o = g
    const int M1 = (g < 3) ? (1024 >> g) : 128;
    descR<128, 32>(Vb + u1h_off(j1), o2p(out, b, c, j1, k), M1, M1 / 128, xi2f(k), lane);
  }
}

extern "C" void kernel_launch(void* const* d_in, const int* in_sizes, int n_in,
                              void* d_out, int out_size, void* d_ws, size_t ws_size,
                              hipStream_t stream) {
  (void)in_sizes; (void)n_in; (void)out_size; (void)ws_size;
  const float* x = (const float*)d_in[0];  // [8, 2048, 6] fp32
  float* out = (float*)d_out;              // [8, 440, 6] fp32
  float2* U1h = (float2*)d_ws;                                       // 8.26 MB
  float2* xh = (float2*)((char*)d_ws + (size_t)48 * U1H_STRIDE * sizeof(float2));
  kA<<<dim3(48), dim3(NTH), 0, stream>>>(x, xh);
  kB<<<dim3(13 * 48), dim3(NTH), 0, stream>>>(xh, U1h, out);
  kC<<<dim3(52 * 48), dim3(NTH), 0, stream>>>(U1h, out);
}